// Round 5
// baseline (412.189 us; speedup 1.0000x reference)
//
#include <hip/hip_runtime.h>
#include <math.h>

typedef _Float16 f16;
typedef _Float16 f16x8 __attribute__((ext_vector_type(8)));
typedef float f32x4 __attribute__((ext_vector_type(4)));

#define LSEQ 200
#define LT 13       // l-tiles of 16 (chunk space 1664 = 13 tiles x 2 ks x 64 lanes)

// One block per sample n. 256 threads = 4 waves.
// R8: occupancy push. R7 fixed the scratch demotion (named frags); kernel ~57us
//   at ~3.7 TB/s = 58% of achievable BW with FETCH == ideal -> MLP-starved:
//   staging is a short phase of a long block, at 4 blocks/CU the HBM pipe idles
//   between staging bursts. Fix: 5 blocks/CU.
//   - e_sw trimmed 28672->26624 B (Tl=13 pad block was never read; guard g<1664)
//     -> LDS total 29648 B, 5 blocks = 148 KB
//   - launch_bounds(256,5): VGPR cap ~102, steady-state liveness ~85 (named frags)
// Watch: if WRITE_SIZE balloons again -> (256,5) re-triggered demotion, revert.
__global__ __launch_bounds__(256, 5)
void capsule_kernel(const float* __restrict__ E,   // [N,200,64]
                    const float* __restrict__ W,   // [64,64]
                    const float* __restrict__ RL,  // [N,3,200]
                    const int* __restrict__ SL,    // [N]
                    float* __restrict__ out)       // [N,3,64]
{
    __shared__ __attribute__((aligned(16))) f16 e_sw[1664*8]; // 26624 B: E A-chunks (read-only after B1)
    __shared__ __attribute__((aligned(16))) f16 w_p[3*224];   //  1344 B: weights, A-frag-permuted layout
    __shared__ __attribute__((aligned(16))) f16 i_c[3*80];    //   480 B: interests rows
    __shared__ __attribute__((aligned(16))) f16 iw_c[3*72];   //   432 B: iW rows (stride 72)
    __shared__ __attribute__((aligned(16))) float cand[192];  //   768 B
    // total 29648 B -> 5 blocks/CU

    const int n = blockIdx.x;
    const int t = threadIdx.x;
    const int lane = t & 63;
    const int wv = t >> 6;
    const int q = lane >> 4;        // quad
    const int cc = lane & 15;       // column within MFMA tile
    const int cmin = cc < 3 ? cc : 2;
    const int o_own = wv*16 + cc;   // this lane's o (and d for the iW exchange)

    // ---- wB: B[k=d][n=o] frags for mappings = E @ W (column gather, L2-hot)
    f16x8 wB0, wB1;
    {
        f16x8 h;
        #pragma unroll
        for (int j = 0; j < 8; j++) h[j] = (f16)W[(q*8 + j)*64 + o_own];
        wB0 = h;
        #pragma unroll
        for (int j = 0; j < 8; j++) h[j] = (f16)W[(32 + q*8 + j)*64 + o_own];
        wB1 = h;
    }

    // ---- initial logits -> registers (owner: lane<16 of wave wv, Tn = wv+4*slot)
    float lg[4][3];
    #pragma unroll
    for (int slot = 0; slot < 4; slot++) {
        int Tn = wv + slot*4;
        if (Tn < LT && lane < 16) {
            int l = Tn*16 + lane;
            if (l < LSEQ) {
                lg[slot][0] = RL[(size_t)n*600 + l];
                lg[slot][1] = RL[(size_t)n*600 + 200 + l];
                lg[slot][2] = RL[(size_t)n*600 + 400 + l];
            }
        }
    }
    const int s = SL[n];

    // ---- zero w_p pad block (all slots of l-pair block p=6, i.e. l in [192,224)).
    //      Valid l=192..199 slots get overwritten by softmax0 after B1.
    if (t < 12) {
        const f16x8 hz = {(f16)0.f,(f16)0.f,(f16)0.f,(f16)0.f,
                          (f16)0.f,(f16)0.f,(f16)0.f,(f16)0.f};
        *(f16x8*)&w_p[(t>>2)*224 + 192 + (t&3)*8] = hz;
    }

    // ---- stage E (fp32 -> f16, A-fragment-swizzled), 7 iters, last partial.
    const float* Eb = E + (size_t)n * (LSEQ*64);
    const float4 f4z = make_float4(0.f, 0.f, 0.f, 0.f);
    #pragma unroll
    for (int i = 0; i < 7; i++) {
        int g = t + i*256;               // 0..1791; chunks >= 1664 don't exist
        if (g < 1664) {
            int sb = g >> 6, c = g & 63;
            int Tl = sb >> 1, ks = sb & 1;
            int qq = c >> 4, m = c & 15;
            int l = Tl*16 + m;
            int kb = ks*32 + qq*8;
            float4 v0 = f4z, v1 = f4z;
            if (l < LSEQ) {
                v0 = *(const float4*)(Eb + l*64 + kb);
                v1 = *(const float4*)(Eb + l*64 + kb + 4);
            }
            f16x8 h = { (f16)v0.x,(f16)v0.y,(f16)v0.z,(f16)v0.w,
                        (f16)v1.x,(f16)v1.y,(f16)v1.z,(f16)v1.w };
            *(f16x8*)&e_sw[g*8] = h;
        }
    }

    __syncthreads();   // B1

    // ---- main matmul: mappings = E @ W, packed into NAMED register B-frags.
    //      mcP covers l-tiles {2P, 2P+1}:
    //      B[k=q*8+j][n=cc] = m[l=(2P + (j>>2))*16 + q*4 + (j&3)][o_own]
    f16x8 mc0, mc1, mc2, mc3, mc4, mc5, mc6;

#define MM_PAIR(P, MC)                                                        \
    {                                                                         \
        f32x4 c0 = {0.f, 0.f, 0.f, 0.f};                                      \
        f32x4 c1 = {0.f, 0.f, 0.f, 0.f};                                      \
        f16x8 a00 = *(f16x8*)&e_sw[(((2*(P)  )*2 + 0)*64 + lane)*8];          \
        c0 = __builtin_amdgcn_mfma_f32_16x16x32_f16(a00, wB0, c0, 0, 0, 0);   \
        f16x8 a01 = *(f16x8*)&e_sw[(((2*(P)  )*2 + 1)*64 + lane)*8];          \
        c0 = __builtin_amdgcn_mfma_f32_16x16x32_f16(a01, wB1, c0, 0, 0, 0);   \
        f16x8 a10 = *(f16x8*)&e_sw[(((2*(P)+1)*2 + 0)*64 + lane)*8];          \
        c1 = __builtin_amdgcn_mfma_f32_16x16x32_f16(a10, wB0, c1, 0, 0, 0);   \
        f16x8 a11 = *(f16x8*)&e_sw[(((2*(P)+1)*2 + 1)*64 + lane)*8];          \
        c1 = __builtin_amdgcn_mfma_f32_16x16x32_f16(a11, wB1, c1, 0, 0, 0);   \
        f16x8 hh;                                                             \
        hh[0]=(f16)c0[0]; hh[1]=(f16)c0[1]; hh[2]=(f16)c0[2]; hh[3]=(f16)c0[3];\
        hh[4]=(f16)c1[0]; hh[5]=(f16)c1[1]; hh[6]=(f16)c1[2]; hh[7]=(f16)c1[3];\
        MC = hh;                                                              \
    }

    MM_PAIR(0, mc0)
    MM_PAIR(1, mc1)
    MM_PAIR(2, mc2)
    MM_PAIR(3, mc3)
    MM_PAIR(4, mc4)
    MM_PAIR(5, mc5)
#undef MM_PAIR
    {   // tail: l-tile 12 only, high half zero
        f32x4 c0 = {0.f, 0.f, 0.f, 0.f};
        f16x8 a00 = *(f16x8*)&e_sw[((12*2 + 0)*64 + lane)*8];
        c0 = __builtin_amdgcn_mfma_f32_16x16x32_f16(a00, wB0, c0, 0, 0, 0);
        f16x8 a01 = *(f16x8*)&e_sw[((12*2 + 1)*64 + lane)*8];
        c0 = __builtin_amdgcn_mfma_f32_16x16x32_f16(a01, wB1, c0, 0, 0, 0);
        f16x8 hh;
        hh[0]=(f16)c0[0]; hh[1]=(f16)c0[1]; hh[2]=(f16)c0[2]; hh[3]=(f16)c0[3];
        hh[4]=(f16)0.f;   hh[5]=(f16)0.f;   hh[6]=(f16)0.f;   hh[7]=(f16)0.f;
        mc6 = hh;
    }

    // ---- wt: B[k=o][n=d] frags for iW = i @ W^T (row-contiguous float4 loads).
    //      Built after the matmul to keep matmul-phase liveness low.
    f16x8 wt0, wt1;
    {
        const float4 a0 = *(const float4*)(W + o_own*64 + q*8);
        const float4 b0 = *(const float4*)(W + o_own*64 + q*8 + 4);
        f16x8 g0 = { (f16)a0.x,(f16)a0.y,(f16)a0.z,(f16)a0.w,
                     (f16)b0.x,(f16)b0.y,(f16)b0.z,(f16)b0.w };
        wt0 = g0;
        const float4 a1 = *(const float4*)(W + o_own*64 + 32 + q*8);
        const float4 b1 = *(const float4*)(W + o_own*64 + 32 + q*8 + 4);
        f16x8 g1 = { (f16)a1.x,(f16)a1.y,(f16)a1.z,(f16)a1.w,
                     (f16)b1.x,(f16)b1.y,(f16)b1.z,(f16)b1.w };
        wt1 = g1;
    }

    // ---- fused softmax0 by logits owners -> w_p (permuted A-frag layout):
    //      slot(l) = (l>>5)*32 + ((l>>2)&3)*8 + ((l>>4)&1)*4 + (l&3)
    #pragma unroll
    for (int slot = 0; slot < 4; slot++) {
        int Tn = wv + slot*4;
        if (Tn < LT && lane < 16) {
            int l = Tn*16 + lane;
            if (l < LSEQ) {
                float w0, w1, w2;
                if (l < s) {
                    float l0 = lg[slot][0], l1 = lg[slot][1], l2 = lg[slot][2];
                    float mx = fmaxf(fmaxf(l0, l1), l2);
                    float e0 = expf(l0 - mx), e1 = expf(l1 - mx), e2 = expf(l2 - mx);
                    float inv = 1.f / (e0 + e1 + e2);
                    w0 = e0*inv; w1 = e1*inv; w2 = e2*inv;
                } else {
                    w0 = w1 = w2 = (1.f/3.f);
                }
                int wbase = (l>>5)*32 + (((l>>2)&3)<<3) + (((l>>4)&1)<<2) + (l&3);
                w_p[wbase]       = (f16)w0;
                w_p[224 + wbase] = (f16)w1;
                w_p[448 + wbase] = (f16)w2;
            }
        }
    }
    __syncthreads();   // B2: w_p ready for cand

    // ---- routing: 3 iterations
    for (int iter = 0; iter < 3; iter++) {
        // cand^T: D[m=caps][n=o_loc] = sum_l w[caps][l] * m[l][o]
        // A = w_p frags (b128 reads, rows 3..15 duplicate caps 2 -> ignored junk),
        // B = named mc register frags.
        f32x4 ca = {0.f, 0.f, 0.f, 0.f};
#define CAND_STEP(P, MC)                                                      \
        { f16x8 a = *(f16x8*)&w_p[cmin*224 + (P)*32 + q*8];                   \
          ca = __builtin_amdgcn_mfma_f32_16x16x32_f16(a, MC, ca, 0, 0, 0); }
        CAND_STEP(0, mc0)
        CAND_STEP(1, mc1)
        CAND_STEP(2, mc2)
        CAND_STEP(3, mc3)
        CAND_STEP(4, mc4)
        CAND_STEP(5, mc5)
        CAND_STEP(6, mc6)
#undef CAND_STEP
        // D rows 0..2 live in lanes q==0 (r = capsule), col cc = o_loc
        if (q == 0) {
            cand[0*64 + o_own] = ca[0];
            cand[1*64 + o_own] = ca[1];
            cand[2*64 + o_own] = ca[2];
        }
        __syncthreads();

        // squash per capsule k (t<192: k=t>>6, o=t&63), write interests or output
        if (t < 192) {
            float x = cand[t];
            float sq = x*x;
            #pragma unroll
            for (int off = 32; off >= 1; off >>= 1) sq += __shfl_xor(sq, off, 64);
            float factor = sq / ((1.f + sq) * sqrtf(sq + 1e-8f));
            float y = factor * x;
            if (iter < 2) {
                i_c[(t >> 6)*80 + (t & 63)] = (f16)y;
            } else {
                out[(size_t)n*192 + t] = y;
            }
        }
        if (iter == 2) break;
        __syncthreads();

        // iW[k][d] = sum_o i[k][o] * W[d][o]: A = i_c frags, B = wt regs.
        // D[m=caps][n=d_loc]; wave wv owns d-tile wv.
        {
            f16x8 ia0 = *(f16x8*)&i_c[cmin*80 + q*8];
            f16x8 ia1 = *(f16x8*)&i_c[cmin*80 + 32 + q*8];
            f32x4 dw = {0.f, 0.f, 0.f, 0.f};
            dw = __builtin_amdgcn_mfma_f32_16x16x32_f16(ia0, wt0, dw, 0, 0, 0);
            dw = __builtin_amdgcn_mfma_f32_16x16x32_f16(ia1, wt1, dw, 0, 0, 0);
            if (q == 0) {
                iw_c[0*72 + o_own] = (f16)dw[0];
                iw_c[1*72 + o_own] = (f16)dw[1];
                iw_c[2*72 + o_own] = (f16)dw[2];
            }
        }
        __syncthreads();   // iw_c exchange complete

        // delta: logits[k][l] += sum_d iW[k][d] * E[l][d]; fused next-softmax.
        // A = iw_c frags, B = ORIGINAL staged E chunks (b128, conflict-free).
        f16x8 iwa0 = *(f16x8*)&iw_c[cmin*72 + q*8];
        f16x8 iwa1 = *(f16x8*)&iw_c[cmin*72 + 32 + q*8];
        #pragma unroll
        for (int slot = 0; slot < 4; slot++) {
            int Tn = wv + slot*4;
            if (Tn < LT) {
                f32x4 da = {0.f, 0.f, 0.f, 0.f};
                f16x8 b0 = *(f16x8*)&e_sw[((Tn*2 + 0)*64 + lane)*8];
                da = __builtin_amdgcn_mfma_f32_16x16x32_f16(iwa0, b0, da, 0, 0, 0);
                f16x8 b1 = *(f16x8*)&e_sw[((Tn*2 + 1)*64 + lane)*8];
                da = __builtin_amdgcn_mfma_f32_16x16x32_f16(iwa1, b1, da, 0, 0, 0);
                if (lane < 16) {
                    int l = Tn*16 + lane;
                    if (l < LSEQ) {
                        float w0, w1, w2;
                        if (l < s) {
                            float l0 = lg[slot][0] + da[0];
                            float l1 = lg[slot][1] + da[1];
                            float l2 = lg[slot][2] + da[2];
                            lg[slot][0] = l0; lg[slot][1] = l1; lg[slot][2] = l2;
                            float mx = fmaxf(fmaxf(l0, l1), l2);
                            float e0 = expf(l0 - mx), e1 = expf(l1 - mx), e2 = expf(l2 - mx);
                            float inv = 1.f / (e0 + e1 + e2);
                            w0 = e0*inv; w1 = e1*inv; w2 = e2*inv;
                        } else {
                            w0 = w1 = w2 = (1.f/3.f);
                        }
                        int wbase = (l>>5)*32 + (((l>>2)&3)<<3) + (((l>>4)&1)<<2) + (l&3);
                        w_p[wbase]       = (f16)w0;
                        w_p[224 + wbase] = (f16)w1;
                        w_p[448 + wbase] = (f16)w2;
                    }
                }
            }
        }
        __syncthreads();
    }
}

extern "C" void kernel_launch(void* const* d_in, const int* in_sizes, int n_in,
                              void* d_out, int out_size, void* d_ws, size_t ws_size,
                              hipStream_t stream) {
    const float* E  = (const float*)d_in[0];
    const float* W  = (const float*)d_in[1];
    const float* RL = (const float*)d_in[2];
    const int*   SL = (const int*)d_in[3];
    float* o = (float*)d_out;
    const int N = in_sizes[3];   // seq_len has N entries
    capsule_kernel<<<dim3(N), dim3(256), 0, stream>>>(E, W, RL, SL, o);
}

// Round 6
// 311.130 us; speedup vs baseline: 1.3248x; 1.3248x over previous
//
#include <hip/hip_runtime.h>
#include <math.h>

typedef _Float16 f16;
typedef _Float16 f16x8 __attribute__((ext_vector_type(8)));
typedef float f32x4 __attribute__((ext_vector_type(4)));

#define LSEQ 200
#define LT 13
#define NCHUNK 1664          // 13 l-tiles x 2 ks x 64 lanes
#define EBUF (NCHUNK*8)      // f16 elements per E buffer
#define SPB 4                // samples per block

// R9: persistent 4-sample blocks, double-buffered E staging, prefetch overlap.
//   Clean kernel (R7-structure) = ~57us vs 33us HBM floor: latency-bound
//   equilibrium -- loads in flight only during the short staging burst.
//   Fix: while computing sample j (buffer j&1), ISSUE the 14 global loads for
//   sample j+1 before the matmul (T14 issue-early), COMMIT (cvt+ds_write into
//   buffer ~j&1) after the matmul. launch_bounds(256,2) -> VGPR cap 256, no
//   demotion risk (R5/R8 demotion was the forced 102-reg cap).
//   LDS 56272 B -> 2 blocks/CU; grid 1024 x 4 samples.
__global__ __launch_bounds__(256, 2)
void capsule_kernel(const float* __restrict__ E,   // [N,200,64]
                    const float* __restrict__ W,   // [64,64]
                    const float* __restrict__ RL,  // [N,3,200]
                    const int* __restrict__ SL,    // [N]
                    float* __restrict__ out,       // [N,3,64]
                    int Ntot)
{
    __shared__ __attribute__((aligned(16))) f16 e_sw[2*EBUF];  // 53248 B
    __shared__ __attribute__((aligned(16))) f16 w_p[3*224];    //  1344 B
    __shared__ __attribute__((aligned(16))) f16 i_c[3*80];     //   480 B
    __shared__ __attribute__((aligned(16))) f16 iw_c[3*72];    //   432 B
    __shared__ __attribute__((aligned(16))) float cand[192];   //   768 B
    // total 56272 B -> 2 blocks/CU

    const int n0 = blockIdx.x * SPB;
    const int t = threadIdx.x;
    const int lane = t & 63;
    const int wv = t >> 6;
    const int q = lane >> 4;        // quad
    const int cc = lane & 15;       // column within MFMA tile
    const int cmin = cc < 3 ? cc : 2;
    const int o_own = wv*16 + cc;   // this lane's o (and d)

    // ---- invariant W frags (once per block)
    f16x8 wB0, wB1, wt0, wt1;
    {
        f16x8 h;
        #pragma unroll
        for (int j = 0; j < 8; j++) h[j] = (f16)W[(q*8 + j)*64 + o_own];
        wB0 = h;
        #pragma unroll
        for (int j = 0; j < 8; j++) h[j] = (f16)W[(32 + q*8 + j)*64 + o_own];
        wB1 = h;
        const float4 a0 = *(const float4*)(W + o_own*64 + q*8);
        const float4 b0 = *(const float4*)(W + o_own*64 + q*8 + 4);
        f16x8 g0 = { (f16)a0.x,(f16)a0.y,(f16)a0.z,(f16)a0.w,
                     (f16)b0.x,(f16)b0.y,(f16)b0.z,(f16)b0.w };
        wt0 = g0;
        const float4 a1 = *(const float4*)(W + o_own*64 + 32 + q*8);
        const float4 b1 = *(const float4*)(W + o_own*64 + 32 + q*8 + 4);
        f16x8 g1 = { (f16)a1.x,(f16)a1.y,(f16)a1.z,(f16)a1.w,
                     (f16)b1.x,(f16)b1.y,(f16)b1.z,(f16)b1.w };
        wt1 = g1;
    }

    // ---- zero w_p pad block (slots for l in [200,224) of each capsule row;
    //      valid l in [192,200) rewritten by softmax0 every sample)
    if (t < 12) {
        const f16x8 hz = {(f16)0.f,(f16)0.f,(f16)0.f,(f16)0.f,
                          (f16)0.f,(f16)0.f,(f16)0.f,(f16)0.f};
        *(f16x8*)&w_p[(t>>2)*224 + 192 + (t&3)*8] = hz;
    }

    // ---- per-thread staging geometry: chunk g_i = t + i*256 (i=0..6; i==6 only t<128)
    //      l = (g>>7)*16 + (g&15); ks = (g>>6)&1; qq = (g>>4)&3; kb = ks*32+qq*8
    const float4 f4z = make_float4(0.f, 0.f, 0.f, 0.f);
    float4 va[7], vb[7];

#define STAGE_ISSUE(NN)                                                       \
    {                                                                         \
        const float* Eb_ = E + (size_t)(NN) * (LSEQ*64);                      \
        _Pragma("unroll")                                                     \
        for (int i = 0; i < 7; i++) {                                         \
            int g = t + i*256;                                                \
            va[i] = f4z; vb[i] = f4z;                                         \
            if (g < NCHUNK) {                                                 \
                int l = (g >> 7)*16 + (g & 15);                               \
                int kb = ((g >> 6) & 1)*32 + ((g >> 4) & 3)*8;                \
                if (l < LSEQ) {                                               \
                    va[i] = *(const float4*)(Eb_ + l*64 + kb);                \
                    vb[i] = *(const float4*)(Eb_ + l*64 + kb + 4);            \
                }                                                             \
            }                                                                 \
        }                                                                     \
    }

#define STAGE_COMMIT(BASE)                                                    \
    {                                                                         \
        _Pragma("unroll")                                                     \
        for (int i = 0; i < 7; i++) {                                         \
            int g = t + i*256;                                                \
            if (g < NCHUNK) {                                                 \
                f16x8 h = { (f16)va[i].x,(f16)va[i].y,(f16)va[i].z,(f16)va[i].w,\
                            (f16)vb[i].x,(f16)vb[i].y,(f16)vb[i].z,(f16)vb[i].w };\
                *(f16x8*)&e_sw[(BASE) + g*8] = h;                             \
            }                                                                 \
        }                                                                     \
    }

    // ---- prologue: stage sample n0 into buffer 0 (cold start)
    if (n0 < Ntot) {
        STAGE_ISSUE(n0)
        STAGE_COMMIT(0)
    }

    for (int j = 0; j < SPB; ++j) {
        const int nn = n0 + j;
        if (nn >= Ntot) break;                      // uniform per block
        const int cur = (j & 1) * EBUF;
        const int nxt = ((j + 1) & 1) * EBUF;
        const bool pf = (j + 1 < SPB) && (nn + 1 < Ntot);

        __syncthreads();   // B1: buffer cur (+ w_p pad on j==0) visible

        // ---- per-sample logits -> registers (owner lane<16, Tn = wv+4*slot)
        float lg[4][3];
        #pragma unroll
        for (int slot = 0; slot < 4; slot++) {
            int Tn = wv + slot*4;
            if (Tn < LT && lane < 16) {
                int l = Tn*16 + lane;
                if (l < LSEQ) {
                    lg[slot][0] = RL[(size_t)nn*600 + l];
                    lg[slot][1] = RL[(size_t)nn*600 + 200 + l];
                    lg[slot][2] = RL[(size_t)nn*600 + 400 + l];
                }
            }
        }
        const int s = SL[nn];

        // ---- PREFETCH: issue next sample's 14 global loads now (in flight
        //      across the matmul below; committed after it).
        if (pf) STAGE_ISSUE(nn + 1)

        // ---- main matmul: mappings = E @ W, packed into NAMED register B-frags.
        //      mcP covers l-tiles {2P,2P+1}: B[k=q*8+j][n=cc] =
        //      m[l=(2P+(j>>2))*16 + q*4 + (j&3)][o_own]
        f16x8 mc0, mc1, mc2, mc3, mc4, mc5, mc6;

#define MM_PAIR(P, MC)                                                        \
        {                                                                     \
            f32x4 c0 = {0.f, 0.f, 0.f, 0.f};                                  \
            f32x4 c1 = {0.f, 0.f, 0.f, 0.f};                                  \
            f16x8 a00 = *(f16x8*)&e_sw[cur + (((2*(P)  )*2 + 0)*64 + lane)*8];\
            c0 = __builtin_amdgcn_mfma_f32_16x16x32_f16(a00, wB0, c0, 0,0,0); \
            f16x8 a01 = *(f16x8*)&e_sw[cur + (((2*(P)  )*2 + 1)*64 + lane)*8];\
            c0 = __builtin_amdgcn_mfma_f32_16x16x32_f16(a01, wB1, c0, 0,0,0); \
            f16x8 a10 = *(f16x8*)&e_sw[cur + (((2*(P)+1)*2 + 0)*64 + lane)*8];\
            c1 = __builtin_amdgcn_mfma_f32_16x16x32_f16(a10, wB0, c1, 0,0,0); \
            f16x8 a11 = *(f16x8*)&e_sw[cur + (((2*(P)+1)*2 + 1)*64 + lane)*8];\
            c1 = __builtin_amdgcn_mfma_f32_16x16x32_f16(a11, wB1, c1, 0,0,0); \
            f16x8 hh;                                                         \
            hh[0]=(f16)c0[0]; hh[1]=(f16)c0[1]; hh[2]=(f16)c0[2]; hh[3]=(f16)c0[3];\
            hh[4]=(f16)c1[0]; hh[5]=(f16)c1[1]; hh[6]=(f16)c1[2]; hh[7]=(f16)c1[3];\
            MC = hh;                                                          \
        }

        MM_PAIR(0, mc0)
        MM_PAIR(1, mc1)
        MM_PAIR(2, mc2)
        MM_PAIR(3, mc3)
        MM_PAIR(4, mc4)
        MM_PAIR(5, mc5)
#undef MM_PAIR
        {   // tail: l-tile 12, high half zero
            f32x4 c0 = {0.f, 0.f, 0.f, 0.f};
            f16x8 a00 = *(f16x8*)&e_sw[cur + ((12*2 + 0)*64 + lane)*8];
            c0 = __builtin_amdgcn_mfma_f32_16x16x32_f16(a00, wB0, c0, 0,0,0);
            f16x8 a01 = *(f16x8*)&e_sw[cur + ((12*2 + 1)*64 + lane)*8];
            c0 = __builtin_amdgcn_mfma_f32_16x16x32_f16(a01, wB1, c0, 0,0,0);
            f16x8 hh;
            hh[0]=(f16)c0[0]; hh[1]=(f16)c0[1]; hh[2]=(f16)c0[2]; hh[3]=(f16)c0[3];
            hh[4]=(f16)0.f;   hh[5]=(f16)0.f;   hh[6]=(f16)0.f;   hh[7]=(f16)0.f;
            mc6 = hh;
        }

        // ---- COMMIT prefetch: loads have had the whole matmul to return.
        if (pf) STAGE_COMMIT(nxt)

        // ---- fused softmax0 -> w_p (permuted A-frag layout):
        //      slot(l) = (l>>5)*32 + ((l>>2)&3)*8 + ((l>>4)&1)*4 + (l&3)
        #pragma unroll
        for (int slot = 0; slot < 4; slot++) {
            int Tn = wv + slot*4;
            if (Tn < LT && lane < 16) {
                int l = Tn*16 + lane;
                if (l < LSEQ) {
                    float w0, w1, w2;
                    if (l < s) {
                        float l0 = lg[slot][0], l1 = lg[slot][1], l2 = lg[slot][2];
                        float mx = fmaxf(fmaxf(l0, l1), l2);
                        float e0 = expf(l0 - mx), e1 = expf(l1 - mx), e2 = expf(l2 - mx);
                        float inv = 1.f / (e0 + e1 + e2);
                        w0 = e0*inv; w1 = e1*inv; w2 = e2*inv;
                    } else {
                        w0 = w1 = w2 = (1.f/3.f);
                    }
                    int wbase = (l>>5)*32 + (((l>>2)&3)<<3) + (((l>>4)&1)<<2) + (l&3);
                    w_p[wbase]       = (f16)w0;
                    w_p[224 + wbase] = (f16)w1;
                    w_p[448 + wbase] = (f16)w2;
                }
            }
        }
        __syncthreads();   // B2: w_p ready

        // ---- routing: 3 iterations
        for (int iter = 0; iter < 3; iter++) {
            f32x4 ca = {0.f, 0.f, 0.f, 0.f};
#define CAND_STEP(P, MC)                                                      \
            { f16x8 a = *(f16x8*)&w_p[cmin*224 + (P)*32 + q*8];               \
              ca = __builtin_amdgcn_mfma_f32_16x16x32_f16(a, MC, ca, 0,0,0); }
            CAND_STEP(0, mc0)
            CAND_STEP(1, mc1)
            CAND_STEP(2, mc2)
            CAND_STEP(3, mc3)
            CAND_STEP(4, mc4)
            CAND_STEP(5, mc5)
            CAND_STEP(6, mc6)
#undef CAND_STEP
            if (q == 0) {
                cand[0*64 + o_own] = ca[0];
                cand[1*64 + o_own] = ca[1];
                cand[2*64 + o_own] = ca[2];
            }
            __syncthreads();

            if (t < 192) {
                float x = cand[t];
                float sq = x*x;
                #pragma unroll
                for (int off = 32; off >= 1; off >>= 1) sq += __shfl_xor(sq, off, 64);
                float factor = sq / ((1.f + sq) * sqrtf(sq + 1e-8f));
                float y = factor * x;
                if (iter < 2) {
                    i_c[(t >> 6)*80 + (t & 63)] = (f16)y;
                } else {
                    out[(size_t)nn*192 + t] = y;
                }
            }
            if (iter == 2) break;
            __syncthreads();

            // iW[k][d] = sum_o i[k][o]*W[d][o]
            {
                f16x8 ia0 = *(f16x8*)&i_c[cmin*80 + q*8];
                f16x8 ia1 = *(f16x8*)&i_c[cmin*80 + 32 + q*8];
                f32x4 dw = {0.f, 0.f, 0.f, 0.f};
                dw = __builtin_amdgcn_mfma_f32_16x16x32_f16(ia0, wt0, dw, 0,0,0);
                dw = __builtin_amdgcn_mfma_f32_16x16x32_f16(ia1, wt1, dw, 0,0,0);
                if (q == 0) {
                    iw_c[0*72 + o_own] = (f16)dw[0];
                    iw_c[1*72 + o_own] = (f16)dw[1];
                    iw_c[2*72 + o_own] = (f16)dw[2];
                }
            }
            __syncthreads();

            // delta: logits[k][l] += sum_d iW[k][d]*E[l][d]; fused next-softmax
            f16x8 iwa0 = *(f16x8*)&iw_c[cmin*72 + q*8];
            f16x8 iwa1 = *(f16x8*)&iw_c[cmin*72 + 32 + q*8];
            #pragma unroll
            for (int slot = 0; slot < 4; slot++) {
                int Tn = wv + slot*4;
                if (Tn < LT) {
                    f32x4 da = {0.f, 0.f, 0.f, 0.f};
                    f16x8 b0 = *(f16x8*)&e_sw[cur + ((Tn*2 + 0)*64 + lane)*8];
                    da = __builtin_amdgcn_mfma_f32_16x16x32_f16(iwa0, b0, da, 0,0,0);
                    f16x8 b1 = *(f16x8*)&e_sw[cur + ((Tn*2 + 1)*64 + lane)*8];
                    da = __builtin_amdgcn_mfma_f32_16x16x32_f16(iwa1, b1, da, 0,0,0);
                    if (lane < 16) {
                        int l = Tn*16 + lane;
                        if (l < LSEQ) {
                            float w0, w1, w2;
                            if (l < s) {
                                float l0 = lg[slot][0] + da[0];
                                float l1 = lg[slot][1] + da[1];
                                float l2 = lg[slot][2] + da[2];
                                lg[slot][0] = l0; lg[slot][1] = l1; lg[slot][2] = l2;
                                float mx = fmaxf(fmaxf(l0, l1), l2);
                                float e0 = expf(l0 - mx), e1 = expf(l1 - mx), e2 = expf(l2 - mx);
                                float inv = 1.f / (e0 + e1 + e2);
                                w0 = e0*inv; w1 = e1*inv; w2 = e2*inv;
                            } else {
                                w0 = w1 = w2 = (1.f/3.f);
                            }
                            int wbase = (l>>5)*32 + (((l>>2)&3)<<3) + (((l>>4)&1)<<2) + (l&3);
                            w_p[wbase]       = (f16)w0;
                            w_p[224 + wbase] = (f16)w1;
                            w_p[448 + wbase] = (f16)w2;
                        }
                    }
                }
            }
            __syncthreads();
        }
    }
#undef STAGE_ISSUE
#undef STAGE_COMMIT
}

extern "C" void kernel_launch(void* const* d_in, const int* in_sizes, int n_in,
                              void* d_out, int out_size, void* d_ws, size_t ws_size,
                              hipStream_t stream) {
    const float* E  = (const float*)d_in[0];
    const float* W  = (const float*)d_in[1];
    const float* RL = (const float*)d_in[2];
    const int*   SL = (const int*)d_in[3];
    float* o = (float*)d_out;
    const int N = in_sizes[3];   // seq_len has N entries
    const int NB = (N + SPB - 1) / SPB;
    capsule_kernel<<<dim3(NB), dim3(256), 0, stream>>>(E, W, RL, SL, o, N);
}